// Round 9
// baseline (118.895 us; speedup 1.0000x reference)
//
#include <hip/hip_runtime.h>

#define HH 128
#define WW 128
#define NPIX 16384
#define NC 32
#define NO 32
#define KS 9
#define TAPS 81
#define DIL 2
#define PAD 8
#define SMAX 27.6310211159f   // s <= SMAX <=> exp(-0.5 s) >= 1e-6; dropped-tap bound ~1.4e-5 << tol
#define NW (NO * NC * TAPS)   // 82944
#define CAP 262144            // fallback-A list capacity

// ---------------------------------------------------------------------------
// Per-pixel mask record: 32 bytes, byte iz = i*3+z holds the 3-bit live mask
// for taps j in {3z,3z+1,3z+2} of row i (bytes 27..31 never read).
// Written byte-owned by prep blocks (no atomics), read as 2x uint4.
// ---------------------------------------------------------------------------
#define BUILD_MASK32(P, M0, M1) do {                                        \
        const uint4* mp_ = (const uint4*)(mask32 + (size_t)(P) * 32);       \
        uint4 ma_ = mp_[0], mb_ = mp_[1];                                   \
        unsigned w_[8] = { ma_.x, ma_.y, ma_.z, ma_.w,                      \
                           mb_.x, mb_.y, mb_.z, mb_.w };                    \
        M0 = 0ull; M1 = 0u;                                                 \
        unsigned m9_[9];                                                    \
        _Pragma("unroll")                                                   \
        for (int i_ = 0; i_ < 9; ++i_) {                                    \
            int k0_ = 3 * i_, k1_ = 3 * i_ + 1, k2_ = 3 * i_ + 2;           \
            unsigned b0_ = (w_[k0_ >> 2] >> ((k0_ & 3) * 8)) & 7u;          \
            unsigned b1_ = (w_[k1_ >> 2] >> ((k1_ & 3) * 8)) & 7u;          \
            unsigned b2_ = (w_[k2_ >> 2] >> ((k2_ & 3) * 8)) & 7u;          \
            m9_[i_] = b0_ | (b1_ << 3) | (b2_ << 6);                        \
        }                                                                   \
        _Pragma("unroll")                                                   \
        for (int i_ = 0; i_ < 7; ++i_)                                      \
            M0 |= (unsigned long long)m9_[i_] << (9 * i_);                  \
        M0 |= (unsigned long long)(m9_[7] & 1u) << 63;                      \
        M1 = (m9_[7] >> 1) | (m9_[8] << 8);                                 \
    } while (0)

// ---------------------------------------------------------------------------
// D1 (prep3): mutually-independent roles by blockIdx.x:
//   [0,1728)    prep: (i, j-third) per block (r8-proven byte-owned mask32 +
//               kbuf[T][pix] for live non-center taps).
//   [1728,1792) transpose W1,W2 -> [tap][o][c] (per-lane contiguous rows).
//   [1792,1856) transpose x -> xT[pix][c] (contiguous channel rows so the
//               layer kernels read 128 B per tap instead of 32 strided words).
// ---------------------------------------------------------------------------
__global__ __launch_bounds__(256) void prep3_kernel(
    const float* __restrict__ x, const float* __restrict__ f,
    const float* __restrict__ W1, const float* __restrict__ W2,
    float* __restrict__ xT, float* __restrict__ kbuf,
    unsigned char* __restrict__ mask32,
    float* __restrict__ W1t, float* __restrict__ W2t)
{
    const int bid = blockIdx.x;
    const int tid = threadIdx.x;

    if (bid < 1728) {                          // ---- prep
        const int pixblk = bid & 63, iz = bid >> 6;   // iz = i*3+z, 0..26
        const int i = iz / 3, z = iz - 3 * i;
        const int pix = pixblk * 256 + tid;
        const int hh = pix >> 7, ww = pix & (WW - 1);
        float fc[NC];
#pragma unroll
        for (int c = 0; c < NC; ++c) fc[c] = f[c * NPIX + pix];
        const int qh = hh + i * DIL - PAD;
        const bool vh = (unsigned)qh < HH;
        unsigned pmask = 0;
#pragma unroll
        for (int jj = 0; jj < 3; ++jj) {
            int j = 3 * z + jj;
            int qw = ww + j * DIL - PAD;
            bool valid = vh & ((unsigned)qw < WW);
            int q = valid ? (qh * WW + qw) : pix;   // safe masked addr
            float s0 = 0.f, s1 = 0.f, s2 = 0.f, s3 = 0.f;
#pragma unroll
            for (int c4 = 0; c4 < 8; ++c4) {
                float d0 = f[(4 * c4 + 0) * NPIX + q] - fc[4 * c4 + 0];
                float d1 = f[(4 * c4 + 1) * NPIX + q] - fc[4 * c4 + 1];
                float d2 = f[(4 * c4 + 2) * NPIX + q] - fc[4 * c4 + 2];
                float d3 = f[(4 * c4 + 3) * NPIX + q] - fc[4 * c4 + 3];
                s0 = fmaf(d0, d0, s0); s1 = fmaf(d1, d1, s1);
                s2 = fmaf(d2, d2, s2); s3 = fmaf(d3, d3, s3);
            }
            float s = (s0 + s1) + (s2 + s3);
            // OOB taps contribute exactly 0 (x zero-padded) -> drop exactly.
            bool live = valid && (s <= SMAX) && !(i == 4 && j == 4);
            if (live) {
                pmask |= 1u << jj;
                kbuf[(i * KS + j) * NPIX + pix] = __expf(-0.5f * s);
            }
        }
        mask32[(size_t)pix * 32 + iz] = (unsigned char)pmask;  // kills poison
        return;
    }

    if (bid < 1792) {                          // ---- W transpose
        for (int t = (bid - 1728) * 256 + tid; t < NW; t += 64 * 256) {
            int o = t / (NC * TAPS);
            int r = t - o * (NC * TAPS);
            int c = r / TAPS;
            int tap = r - c * TAPS;
            int d = (tap * NO + o) * NC + c;
            W1t[d] = W1[t];
            W2t[d] = W2[t];
        }
        return;
    }

    // ---- [1792,1856): x transpose -> xT[pix][c]
    for (int idx = (bid - 1792) * 256 + tid; idx < NPIX * NC; idx += 64 * 256) {
        int p = idx >> 5, c = idx & 31;
        xT[idx] = x[c * NPIX + p];             // writes fully coalesced
    }
}

// ---------------------------------------------------------------------------
// layer_kernel: one PAC layer, one pixel per half-wave, lane = output o.
//   acc = bias[o] + sum over {center} u live(p):  kv_T * ( W[T][o][.] . in(q_T) )
// in is [pix][c] (contiguous rows -> 8 broadcast float4 loads per tap);
// W is [tap][o][c] (per-lane contiguous row -> 8 float4 loads);
// kv from kbuf (broadcast), center tap kv = 1 exactly.
// Sole writer per (p,o): plain stores, no atomics, no pre-zeroing.
// strided=0: write outp[p*NC+o] ([pix][c], feeds next layer);
// strided=1: write outp[o*NPIX+p] (final [o][pix] output layout).
// Single-level walk: worst pixel ~6 taps -> ~us-scale chains (the r7/r8
// 44us back2 tail was the NESTED walk; eliminated by materializing h).
// ---------------------------------------------------------------------------
__global__ __launch_bounds__(256) void layer_kernel(
    const float* __restrict__ inT, const float* __restrict__ kbuf,
    const unsigned char* __restrict__ mask32, const float* __restrict__ Wt,
    const float* __restrict__ bias, float* __restrict__ outp, int strided)
{
    const int hw = threadIdx.x >> 5;           // 0..7
    const int lane = threadIdx.x & 31;         // output channel o
    const int p = blockIdx.x * 8 + hw;

    unsigned long long A0; unsigned A1;
    BUILD_MASK32(p, A0, A1);

    float acc = bias[lane];

#define TAP_BODY(T, Q, KV) do {                                            \
        const float4* xp_ = (const float4*)(inT + (Q) * NC);               \
        const float4* wp_ = (const float4*)(Wt + ((T) * NO + lane) * NC);  \
        float t0_ = 0.f, t1_ = 0.f, t2_ = 0.f, t3_ = 0.f;                  \
        _Pragma("unroll")                                                  \
        for (int c4_ = 0; c4_ < 8; ++c4_) {                                \
            float4 x4_ = xp_[c4_];                                         \
            float4 w4_ = wp_[c4_];                                         \
            t0_ = fmaf(w4_.x, x4_.x, t0_);                                 \
            t1_ = fmaf(w4_.y, x4_.y, t1_);                                 \
            t2_ = fmaf(w4_.z, x4_.z, t2_);                                 \
            t3_ = fmaf(w4_.w, x4_.w, t3_);                                 \
        }                                                                  \
        acc = fmaf((KV), (t0_ + t1_) + (t2_ + t3_), acc);                  \
    } while (0)

    // center tap (T=40, q=p, kv=1 exactly)
    TAP_BODY(40, p, 1.0f);

    // masked taps, ascending T; q always in-bounds by prep construction
    while (A0) {
        int T = __builtin_ctzll(A0);
        A0 &= A0 - 1;
        int ii = T / KS, jj = T - KS * ii;
        int q = p + (ii * DIL - PAD) * WW + (jj * DIL - PAD);
        float kv = kbuf[T * NPIX + p];
        TAP_BODY(T, q, kv);
    }
    while (A1) {
        int T = 64 + __builtin_ctz(A1);
        A1 &= A1 - 1;
        int ii = T / KS, jj = T - KS * ii;
        int q = p + (ii * DIL - PAD) * WW + (jj * DIL - PAD);
        float kv = kbuf[T * NPIX + p];
        TAP_BODY(T, q, kv);
    }
#undef TAP_BODY

    if (strided) outp[lane * NPIX + p] = acc;
    else         outp[p * NC + lane] = acc;
}

// ===========================================================================
// Fallback path A (round-5 proven, 126.9 us): 4 classic dispatches.
// ===========================================================================
__global__ __launch_bounds__(64) void zero_cnt_kernel(unsigned* __restrict__ cnt)
{
    if (threadIdx.x == 0) *cnt = 0u;
}

__device__ __forceinline__ void sparse_body(
    const float* __restrict__ in, const float* __restrict__ Wt,
    const unsigned* __restrict__ cnt, const uint2* __restrict__ list,
    float* __restrict__ out, unsigned gid, unsigned stride)
{
    unsigned n = *cnt;
    if (n > CAP) n = CAP;
    const unsigned total = n * 32u;
    for (unsigned it = gid; it < total; it += stride) {
        unsigned e = it >> 5;
        int o = (int)(it & 31u);
        uint2 me = list[e];
        int pix = (int)(me.x & 16383u);
        int T = (int)(me.x >> 14);
        float kv = __uint_as_float(me.y);
        int ii = T / KS, jj = T - KS * ii;
        int q = pix + (ii * DIL - PAD) * WW + (jj * DIL - PAD);
        const float4* __restrict__ wp =
            (const float4*)(Wt + (T * NO + o) * NC);
        float t0 = 0.f, t1 = 0.f, t2 = 0.f, t3 = 0.f;
#pragma unroll
        for (int c4 = 0; c4 < 8; ++c4) {
            float4 w4 = wp[c4];
            t0 = fmaf(in[(4 * c4 + 0) * NPIX + q], w4.x, t0);
            t1 = fmaf(in[(4 * c4 + 1) * NPIX + q], w4.y, t1);
            t2 = fmaf(in[(4 * c4 + 2) * NPIX + q], w4.z, t2);
            t3 = fmaf(in[(4 * c4 + 3) * NPIX + q], w4.w, t3);
        }
        atomicAdd(&out[o * NPIX + pix], kv * ((t0 + t1) + (t2 + t3)));
    }
}

__global__ __launch_bounds__(256) void front_kernel(
    const float* __restrict__ x, const float* __restrict__ f,
    const float* __restrict__ W1, const float* __restrict__ W2,
    const float* __restrict__ b1,
    float* __restrict__ h, unsigned* __restrict__ cnt,
    uint2* __restrict__ list, float* __restrict__ W1t,
    float* __restrict__ W2t, float* __restrict__ outz)
{
    const int y = blockIdx.y;
    const int tid = threadIdx.x;

    if (y < 41) {
        const int pix = blockIdx.x * 256 + tid;
        const int hh = pix >> 7, ww = pix & (WW - 1);
        float fc[NC];
#pragma unroll
        for (int c = 0; c < NC; ++c) fc[c] = f[c * NPIX + pix];
#pragma unroll
        for (int u = 0; u < 2; ++u) {
            int T = 2 * y + u;
            if (T >= TAPS || T == 40) continue;
            int ii = T / KS, jj = T - KS * ii;
            int qh = hh + ii * DIL - PAD;
            int qw = ww + jj * DIL - PAD;
            bool valid = ((unsigned)qh < HH) & ((unsigned)qw < WW);
            int q = valid ? (qh * WW + qw) : pix;
            float s0 = 0.f, s1 = 0.f, s2 = 0.f, s3 = 0.f;
#pragma unroll
            for (int c4 = 0; c4 < 8; ++c4) {
                float d0 = f[(4 * c4 + 0) * NPIX + q] - fc[4 * c4 + 0];
                float d1 = f[(4 * c4 + 1) * NPIX + q] - fc[4 * c4 + 1];
                float d2 = f[(4 * c4 + 2) * NPIX + q] - fc[4 * c4 + 2];
                float d3 = f[(4 * c4 + 3) * NPIX + q] - fc[4 * c4 + 3];
                s0 = fmaf(d0, d0, s0); s1 = fmaf(d1, d1, s1);
                s2 = fmaf(d2, d2, s2); s3 = fmaf(d3, d3, s3);
            }
            float s = (s0 + s1) + (s2 + s3);
            if (valid && (s <= SMAX)) {
                unsigned idx = atomicAdd(cnt, 1u);
                if (idx < CAP)
                    list[idx] = make_uint2(
                        (unsigned)pix | ((unsigned)T << 14),
                        __float_as_uint(__expf(-0.5f * s)));
            }
        }
        return;
    }

    if (y < 49) {
        const int o0 = (y - 41) * 4;
        __shared__ float wsm[4 * NC];
        if (tid < 128) {
            int o = tid >> 5, c = tid & 31;
            wsm[tid] = W1[((o0 + o) * NC + c) * TAPS + 40];
        }
        __syncthreads();
        const int pix = blockIdx.x * 256 + tid;
        float x0[NC];
#pragma unroll
        for (int c = 0; c < NC; ++c) x0[c] = x[c * NPIX + pix];
        float a0 = 0.f, a1 = 0.f, a2 = 0.f, a3 = 0.f;
#pragma unroll
        for (int c = 0; c < NC; ++c) {
            float xv = x0[c];
            a0 = fmaf(xv, wsm[0 * NC + c], a0);
            a1 = fmaf(xv, wsm[1 * NC + c], a1);
            a2 = fmaf(xv, wsm[2 * NC + c], a2);
            a3 = fmaf(xv, wsm[3 * NC + c], a3);
        }
        h[(o0 + 0) * NPIX + pix] = a0 + b1[o0 + 0];
        h[(o0 + 1) * NPIX + pix] = a1 + b1[o0 + 1];
        h[(o0 + 2) * NPIX + pix] = a2 + b1[o0 + 2];
        h[(o0 + 3) * NPIX + pix] = a3 + b1[o0 + 3];
        return;
    }

    if (y == 49) {
        float4 z = make_float4(0.f, 0.f, 0.f, 0.f);
        for (int t = blockIdx.x * 256 + tid; t < (NO * NPIX) / 4; t += 64 * 256)
            ((float4*)outz)[t] = z;
        return;
    }

    for (int t = blockIdx.x * 256 + tid; t < NW; t += 64 * 256) {
        int o = t / (NC * TAPS);
        int r = t - o * (NC * TAPS);
        int c = r / TAPS;
        int tap = r - c * TAPS;
        int d = (tap * NO + o) * NC + c;
        W1t[d] = W1[t];
        W2t[d] = W2[t];
    }
}

__global__ __launch_bounds__(256) void sparse1_kernel(
    const float* __restrict__ x, const float* __restrict__ W1t,
    const unsigned* __restrict__ cnt, const uint2* __restrict__ list,
    float* __restrict__ h)
{
    sparse_body(x, W1t, cnt, list, h,
                blockIdx.x * 256 + threadIdx.x, gridDim.x * 256);
}

__global__ __launch_bounds__(256) void back_kernel(
    const float* __restrict__ h, const float* __restrict__ W2,
    const float* __restrict__ W2t, const float* __restrict__ b2,
    const unsigned* __restrict__ cnt, const uint2* __restrict__ list,
    float* __restrict__ out)
{
    const int y = blockIdx.y;
    const int tid = threadIdx.x;
    if (y < 8) {
        const int o0 = y * 4;
        __shared__ float wsm[4 * NC];
        if (tid < 128) {
            int o = tid >> 5, c = tid & 31;
            wsm[tid] = W2[((o0 + o) * NC + c) * TAPS + 40];
        }
        __syncthreads();
        const int pix = blockIdx.x * 256 + tid;
        float h0[NC];
#pragma unroll
        for (int c = 0; c < NC; ++c) h0[c] = h[c * NPIX + pix];
        float a0 = 0.f, a1 = 0.f, a2 = 0.f, a3 = 0.f;
#pragma unroll
        for (int c = 0; c < NC; ++c) {
            float hv = h0[c];
            a0 = fmaf(hv, wsm[0 * NC + c], a0);
            a1 = fmaf(hv, wsm[1 * NC + c], a1);
            a2 = fmaf(hv, wsm[2 * NC + c], a2);
            a3 = fmaf(hv, wsm[3 * NC + c], a3);
        }
        atomicAdd(&out[(o0 + 0) * NPIX + pix], a0 + b2[o0 + 0]);
        atomicAdd(&out[(o0 + 1) * NPIX + pix], a1 + b2[o0 + 1]);
        atomicAdd(&out[(o0 + 2) * NPIX + pix], a2 + b2[o0 + 2]);
        atomicAdd(&out[(o0 + 3) * NPIX + pix], a3 + b2[o0 + 3]);
        return;
    }
    sparse_body(h, W2t, cnt, list, out,
                blockIdx.x * 256 + tid, 64 * 256);
}

// ===========================================================================
// Fallback path B (tiny ws): fused per-layer, original W layout.
// ===========================================================================
#define CHUNK 27
#define NCHUNK 3
#define KMIN 1e-6f
__global__ __launch_bounds__(256) void pac_layer_fuse(
    const float* __restrict__ in, const float* __restrict__ f,
    const float* __restrict__ Wt, const float* __restrict__ bias,
    float* __restrict__ out)
{
    __shared__ float wl[NC * CHUNK * 8];
    const int og = blockIdx.y;
    const int pix = blockIdx.x * 256 + threadIdx.x;
    const int h = pix >> 7, w = pix & (WW - 1);
    float acc[8];
#pragma unroll
    for (int i = 0; i < 8; ++i) acc[i] = 0.f;
    float fc[NC];
#pragma unroll
    for (int c = 0; c < NC; ++c) fc[c] = f[c * NPIX + pix];
    for (int ch = 0; ch < NCHUNK; ++ch) {
        __syncthreads();
        for (int idx = threadIdx.x; idx < NC * CHUNK * 8; idx += 256) {
            int t = idx % CHUNK;
            int c = (idx / CHUNK) % NC;
            int o = idx / (CHUNK * NC);
            wl[(c * CHUNK + t) * 8 + o] =
                Wt[(og * 8 + o) * (NC * TAPS) + c * TAPS + ch * CHUNK + t];
        }
        __syncthreads();
        for (int t = 0; t < CHUNK; ++t) {
            int tap = ch * CHUNK + t;
            int qh = h + (tap / KS) * DIL - PAD;
            int qw = w + (tap % KS) * DIL - PAD;
            bool valid = ((unsigned)qh < HH) & ((unsigned)qw < WW);
            int q = qh * WW + qw;
            float s = 0.f;
#pragma unroll
            for (int c = 0; c < NC; ++c) {
                float fn = valid ? f[c * NPIX + q] : 0.f;
                float d = fn - fc[c];
                s = fmaf(d, d, s);
            }
            float kv = __expf(-0.5f * s);
            if (__all((kv < KMIN) | (!valid))) continue;
            const float* wpp = &wl[t * 8];
#pragma unroll 8
            for (int c = 0; c < NC; ++c) {
                float v = valid ? in[c * NPIX + q] : 0.f;
                v *= kv;
#pragma unroll
                for (int o = 0; o < 8; ++o)
                    acc[o] = fmaf(v, wpp[c * CHUNK * 8 + o], acc[o]);
            }
        }
    }
#pragma unroll
    for (int o = 0; o < 8; ++o)
        out[(og * 8 + o) * NPIX + pix] = acc[o] + bias[og * 8 + o];
}

// ---------------------------------------------------------------------------
extern "C" void kernel_launch(void* const* d_in, const int* in_sizes, int n_in,
                              void* d_out, int out_size, void* d_ws, size_t ws_size,
                              hipStream_t stream)
{
    (void)in_sizes; (void)n_in; (void)out_size;
    const float* x  = (const float*)d_in[0];
    const float* f  = (const float*)d_in[1];
    const float* W1 = (const float*)d_in[2];
    const float* b1 = (const float*)d_in[3];
    const float* W2 = (const float*)d_in[4];
    const float* b2 = (const float*)d_in[5];
    float* out = (float*)d_out;

    float* ws = (float*)d_ws;
    // main (3-dispatch) layout
    float* xT   = ws;                                   // NPIX*NC
    float* hT   = xT + NPIX * NC;                       // NPIX*NO
    float* kbuf = hT + NPIX * NO;                       // TAPS*NPIX
    float* W1t  = kbuf + TAPS * NPIX;                   // NW
    float* W2t  = W1t + NW;                             // NW
    unsigned char* mask32 = (unsigned char*)(W2t + NW); // NPIX*32 B
    const size_t need_main =
        (size_t)(NPIX * NC + NPIX * NO + TAPS * NPIX + 2 * NW) * 4
        + (size_t)NPIX * 32;
    // fallback-A layout
    float* hA   = ws;
    float* W1tA = ws + NO * NPIX;
    float* W2tA = W1tA + NW;
    unsigned* cnt = (unsigned*)(W2tA + NW);
    uint2* list = (uint2*)(cnt + 16);
    const size_t need_fb =
        (size_t)(NO * NPIX + 2 * NW + 16) * 4 + (size_t)CAP * 8;

    if (ws_size >= need_main) {
        prep3_kernel<<<dim3(1856), 256, 0, stream>>>(
            x, f, W1, W2, xT, kbuf, mask32, W1t, W2t);
        layer_kernel<<<dim3(2048), 256, 0, stream>>>(
            xT, kbuf, mask32, W1t, b1, hT, 0);
        layer_kernel<<<dim3(2048), 256, 0, stream>>>(
            hT, kbuf, mask32, W2t, b2, out, 1);
    } else if (ws_size >= need_fb) {
        zero_cnt_kernel<<<dim3(1), 64, 0, stream>>>(cnt);
        front_kernel<<<dim3(64, 51), 256, 0, stream>>>(
            x, f, W1, W2, b1, hA, cnt, list, W1tA, W2tA, out);
        sparse1_kernel<<<dim3(128), 256, 0, stream>>>(x, W1tA, cnt, list, hA);
        back_kernel<<<dim3(64, 9), 256, 0, stream>>>(
            hA, W2, W2tA, b2, cnt, list, out);
    } else {
        float* hbuf = ws;
        pac_layer_fuse<<<dim3(64, 4), 256, 0, stream>>>(x, f, W1, b1, hbuf);
        pac_layer_fuse<<<dim3(64, 4), 256, 0, stream>>>(hbuf, f, W2, b2, out);
    }
}